// Round 2
// baseline (943.684 us; speedup 1.0000x reference)
//
#include <hip/hip_runtime.h>
#include <hip/hip_bf16.h>
#include <cstdint>
#include <cstddef>

// ---------- types ----------
using u16 = unsigned short;
typedef __attribute__((ext_vector_type(4))) float f32x4;
typedef __attribute__((ext_vector_type(8))) unsigned short u16x8;
typedef __attribute__((ext_vector_type(4))) unsigned short u16x4;
typedef __bf16 bfrag __attribute__((ext_vector_type(8)));   // 8 bf16 = 4 VGPR MFMA operand

constexpr int Hn = 8, Cn = 1024, Dn = 128, Fn = 512, Bn = 16;
constexpr int M1 = Bn * Cn;  // 16384 rows of x / att_out

// workspace layout (bytes)
constexpr size_t OFF_XB  = 0;                                  // x bf16 [16384][512]
constexpr size_t SZ_XB   = (size_t)M1 * Fn * 2;                // 16 MiB
constexpr size_t OFF_WT  = OFF_XB + SZ_XB;                     // Wt bf16 [3][1024][512] (q,k,v)
constexpr size_t SZ_WT   = 3ull * 1024 * 512 * 2;              // 3 MiB
constexpr size_t OFF_W0T = OFF_WT + SZ_WT;                     // Ww0^T bf16 [128][1024]
constexpr size_t SZ_W0T  = 128ull * 1024 * 2;
constexpr size_t OFF_Q   = OFF_W0T + SZ_W0T;                   // q perm [16][8][1024][128] bf16
constexpr size_t SZ_P    = (size_t)Bn * Hn * Cn * Dn * 2;      // 32 MiB each
constexpr size_t OFF_K   = OFF_Q + SZ_P;
constexpr size_t OFF_V   = OFF_K + SZ_P;
constexpr size_t OFF_ATT = OFF_V + SZ_P;                       // vals2 bf16 [16384][1024]

// ---------- helpers ----------
__device__ __forceinline__ float bf2f(u16 u) {
  unsigned int x = ((unsigned int)u) << 16;
  return __builtin_bit_cast(float, x);
}
__device__ __forceinline__ u16 f2bf(float f) {
  unsigned int u = __builtin_bit_cast(unsigned int, f);
  u += 0x7fffu + ((u >> 16) & 1u);   // RNE
  return (u16)(u >> 16);
}
__device__ __forceinline__ f32x4 mfma16(bfrag a, bfrag b, f32x4 c) {
  return __builtin_amdgcn_mfma_f32_16x16x32_bf16(a, b, c, 0, 0, 0);
}
// async 16B global->LDS; lds base must be wave-uniform (lane*16 auto-offset)
__device__ __forceinline__ void gload16(const void* g, void* lds) {
  __builtin_amdgcn_global_load_lds(
      (const __attribute__((address_space(1))) unsigned int*)g,
      (__attribute__((address_space(3))) unsigned int*)lds, 16, 0, 0);
}

// ---------- prep kernels ----------
__global__ void cvt_bf16(const float* __restrict__ in, u16* __restrict__ out, int n) {
  int idx = (blockIdx.x * blockDim.x + threadIdx.x) * 4;
  if (idx < n) {
    float4 v = *(const float4*)(in + idx);
    u16x4 o;
    o.x = f2bf(v.x); o.y = f2bf(v.y); o.z = f2bf(v.z); o.w = f2bf(v.w);
    *(u16x4*)(out + idx) = o;
  }
}

// in [R][Cc] f32 -> out [Cc][R] bf16 ; block (32,8), grid (Cc/32, R/32)
__global__ void transpose_cvt(const float* __restrict__ in, u16* __restrict__ out,
                              int R, int Cc) {
  __shared__ float tile[32][33];
  int c0 = blockIdx.x * 32, r0 = blockIdx.y * 32;
  int tx = threadIdx.x, ty = threadIdx.y;
#pragma unroll
  for (int i = 0; i < 4; ++i)
    tile[ty + i * 8][tx] = in[(size_t)(r0 + ty + i * 8) * Cc + c0 + tx];
  __syncthreads();
#pragma unroll
  for (int i = 0; i < 4; ++i)
    out[(size_t)(c0 + ty + i * 8) * R + r0 + tx] = f2bf(tile[tx][ty + i * 8]);
}

// ---------- QKV projection GEMM ----------
__global__ void qkv_gemm(const u16* __restrict__ xb, const u16* __restrict__ wt,
                         const float* __restrict__ bq, const float* __restrict__ bk,
                         const float* __restrict__ bv,
                         u16* __restrict__ qout, u16* __restrict__ kout,
                         u16* __restrict__ vout) {
  __shared__ u16 As[128 * 64];
  __shared__ u16 Bs[128 * 64];
  const int m0 = blockIdx.x * 128;
  const int n0 = blockIdx.y * 128;
  const int p  = blockIdx.z;
  const u16* wp = wt + (size_t)p * 1024 * 512;
  const float* bias = (p == 0) ? bq : (p == 1) ? bk : bv;
  u16* outp = (p == 0) ? qout : (p == 1) ? kout : vout;

  const int tid = threadIdx.x, l = tid & 63, w = tid >> 6;
  const int lr = l & 15, lg = l >> 4;
  const int wr = w >> 1, wc = w & 1;

  f32x4 acc[4][4] = {};

  for (int kt = 0; kt < Fn; kt += 64) {
#pragma unroll
    for (int i = 0; i < 4; ++i) {
      int chb = (i * 4 + w) * 64;
      int ch = chb + l;
      int row = ch >> 3, scc = (ch & 7) ^ (row & 7);
      gload16(xb + (size_t)(m0 + row) * Fn + kt + scc * 8, &As[chb * 8]);
    }
#pragma unroll
    for (int i = 0; i < 4; ++i) {
      int chb = (i * 4 + w) * 64;
      int ch = chb + l;
      int row = ch >> 3, scc = (ch & 7) ^ (row & 7);
      gload16(wp + (size_t)(n0 + row) * Fn + kt + scc * 8, &Bs[chb * 8]);
    }
    __syncthreads();
#pragma unroll
    for (int kk = 0; kk < 2; ++kk) {
      bfrag af[4], bf_[4];
#pragma unroll
      for (int fm = 0; fm < 4; ++fm) {
        int row = wr * 64 + fm * 16 + lr;
        int off = (kk * 4 + lg) ^ (row & 7);
        af[fm] = *(const bfrag*)&As[row * 64 + off * 8];
      }
#pragma unroll
      for (int fn = 0; fn < 4; ++fn) {
        int row = wc * 64 + fn * 16 + lr;
        int off = (kk * 4 + lg) ^ (row & 7);
        bf_[fn] = *(const bfrag*)&Bs[row * 64 + off * 8];
      }
#pragma unroll
      for (int fm = 0; fm < 4; ++fm)
#pragma unroll
        for (int fn = 0; fn < 4; ++fn)
          acc[fm][fn] = mfma16(af[fm], bf_[fn], acc[fm][fn]);
    }
    __syncthreads();
  }

  // epilogue: perm write  (h'=c>>7, c'=(c&127)*8+(j>>7), d=j&127)
#pragma unroll
  for (int fm = 0; fm < 4; ++fm) {
#pragma unroll
    for (int r = 0; r < 4; ++r) {
      int m = m0 + wr * 64 + fm * 16 + lg * 4 + r;
      int b = m >> 10, c = m & 1023;
      int gh = c >> 7;
#pragma unroll
      for (int fn = 0; fn < 4; ++fn) {
        int j = n0 + wc * 64 + fn * 16 + lr;
        float v = acc[fm][fn][r] + bias[j];
        int ii = ((c & 127) << 3) | (j >> 7);
        int d = j & 127;
        size_t idx = (((size_t)(b * 8 + gh) * 1024 + ii) << 7) | d;
        outp[idx] = f2bf(v);
      }
    }
  }
}

// ---------- fused flash attention ----------
// O = softmax(QK^T/sqrt(D))@V - V.  1024 blocks (XCD-swizzled), 4 waves,
// wave owns 32 q-rows.  2-phase pipeline: K dbuf via global_load_lds issued a
// full iter ahead; V dbuf via reg-stage (issue-early / ds_write-late); one
// barrier per iteration (P tile is per-wave -> no barrier needed for it).
// LDS 80KB -> 2 blocks/CU.
__global__ void attn_kernel(const u16* __restrict__ qp_all, const u16* __restrict__ kp_all,
                            const u16* __restrict__ vp_all, u16* __restrict__ attout) {
  __shared__ u16 Ks[2][64 * 128];   // [kv][f] linear, source-preswizzled chunks
  __shared__ u16 Vt[2][128 * 64];   // V^T [d][kv], chunk-XOR swizzled
  __shared__ u16 Ps[4][32 * 64];    // per-wave P [q][kv], chunk-XOR swizzled

  // XCD-aware bijective swizzle: XCD k owns heads 16k..16k+15 (all q-tiles)
  const int bid = blockIdx.x;
  const int wg = (bid & 7) * 128 + (bid >> 3);
  const int bh = wg >> 3;
  const int qt = wg & 7;

  const int tid = threadIdx.x, l = tid & 63, w = tid >> 6;
  const int lr = l & 15, lg = l >> 4;

  const u16* qp = qp_all + (size_t)bh * (Cn * Dn);
  const u16* kp = kp_all + (size_t)bh * (Cn * Dn);
  const u16* vp = vp_all + (size_t)bh * (Cn * Dn);
  const int qr0 = qt * 128 + w * 32;

  // Q fragments in registers for the whole kernel
  bfrag aq[2][4];
#pragma unroll
  for (int fm = 0; fm < 2; ++fm)
#pragma unroll
    for (int kk = 0; kk < 4; ++kk)
      aq[fm][kk] = *(const bfrag*)(qp + (size_t)(qr0 + fm * 16 + lr) * Dn + kk * 32 + lg * 8);

  f32x4 o[2][8] = {};
  float mst[2][4], lst[2][4];
#pragma unroll
  for (int a = 0; a < 2; ++a)
#pragma unroll
    for (int r = 0; r < 4; ++r) { mst[a][r] = -1e30f; lst[a][r] = 0.f; }

  const float cl2 = 0.12751744f;  // log2(e)/sqrt(128): softmax in exp2 domain

  // ---- prologue: stage tile 0 (K -> Ks[0], V -> regs -> Vt[0]) ----
#pragma unroll
  for (int i = 0; i < 4; ++i) {
    int chb = (i * 4 + w) * 64;
    int ch = chb + l;
    int row = ch >> 4, scc = (ch & 15) ^ (row & 7);
    gload16(kp + (size_t)row * Dn + scc * 8, &Ks[0][chb * 8]);
  }
  {
    const u16* vr = vp + (size_t)l * Dn + w * 32;
    u16x8 vreg[4];
#pragma unroll
    for (int i = 0; i < 4; ++i) vreg[i] = *(const u16x8*)(vr + i * 8);
#pragma unroll
    for (int i = 0; i < 4; ++i)
#pragma unroll
      for (int j2 = 0; j2 < 8; ++j2) {
        int d = w * 32 + i * 8 + j2;
        Vt[0][d * 64 + (((l >> 3) ^ (d & 7)) << 3) + (l & 7)] = vreg[i][j2];
      }
  }
  __syncthreads();

  for (int t = 0; t < 16; ++t) {
    const int cur = t & 1, nxt = cur ^ 1;
    const bool pre = (t < 15);
    u16x8 vreg[4];

    // issue next tile's loads first (hidden under this iter's compute)
    if (pre) {
#pragma unroll
      for (int i = 0; i < 4; ++i) {
        int chb = (i * 4 + w) * 64;
        int ch = chb + l;
        int row = ch >> 4, scc = (ch & 15) ^ (row & 7);
        gload16(kp + (size_t)((t + 1) * 64 + row) * Dn + scc * 8, &Ks[nxt][chb * 8]);
      }
      const u16* vr = vp + (size_t)((t + 1) * 64 + l) * Dn + w * 32;
#pragma unroll
      for (int i = 0; i < 4; ++i) vreg[i] = *(const u16x8*)(vr + i * 8);
    }

    // S = Q K^T  (per wave: [32 q][64 kv])
    f32x4 s[2][4] = {};
#pragma unroll
    for (int kk = 0; kk < 4; ++kk) {
      bfrag bk_[4];
#pragma unroll
      for (int fn = 0; fn < 4; ++fn) {
        int row = fn * 16 + lr;
        int off = (kk * 4 + lg) ^ (row & 7);
        bk_[fn] = *(const bfrag*)&Ks[cur][row * 128 + off * 8];
      }
#pragma unroll
      for (int fm = 0; fm < 2; ++fm)
#pragma unroll
        for (int fn = 0; fn < 4; ++fn)
          s[fm][fn] = mfma16(aq[fm][kk], bk_[fn], s[fm][fn]);
    }

    // online softmax in exp2 domain (scale folded)
#pragma unroll
    for (int fm = 0; fm < 2; ++fm) {
#pragma unroll
      for (int r = 0; r < 4; ++r) {
        float mx = fmaxf(fmaxf(s[fm][0][r], s[fm][1][r]), fmaxf(s[fm][2][r], s[fm][3][r]));
#pragma unroll
        for (int mk = 1; mk < 16; mk <<= 1) mx = fmaxf(mx, __shfl_xor(mx, mk, 64));
        float mold = mst[fm][r];
        float mnew = fmaxf(mold, mx * cl2);
        float alpha = exp2f(mold - mnew);
        mst[fm][r] = mnew;
        float rs = 0.f;
#pragma unroll
        for (int fn = 0; fn < 4; ++fn) {
          float pv = exp2f(fmaf(s[fm][fn][r], cl2, -mnew));
          s[fm][fn][r] = pv;
          rs += pv;
        }
#pragma unroll
        for (int mk = 1; mk < 16; mk <<= 1) rs += __shfl_xor(rs, mk, 64);
        lst[fm][r] = lst[fm][r] * alpha + rs;
#pragma unroll
        for (int fn2 = 0; fn2 < 8; ++fn2) o[fm][fn2][r] *= alpha;
      }
    }

    // P -> per-wave LDS (swizzled); no barrier needed (own wave only)
#pragma unroll
    for (int fm = 0; fm < 2; ++fm)
#pragma unroll
      for (int fn = 0; fn < 4; ++fn)
#pragma unroll
        for (int r = 0; r < 4; ++r) {
          int q = fm * 16 + lg * 4 + r;
          int col = fn * 16 + lr;
          Ps[w][q * 64 + ((((col >> 3)) ^ (q & 7)) << 3) + (col & 7)] = f2bf(s[fm][fn][r]);
        }

    // PV
#pragma unroll
    for (int kk = 0; kk < 2; ++kk) {
      bfrag ap[2];
#pragma unroll
      for (int fm = 0; fm < 2; ++fm) {
        int q = fm * 16 + lr;
        int off = (kk * 4 + lg) ^ (q & 7);
        ap[fm] = *(const bfrag*)&Ps[w][q * 64 + off * 8];
      }
#pragma unroll
      for (int fn2 = 0; fn2 < 8; ++fn2) {
        int d = fn2 * 16 + lr;
        int off = (kk * 4 + lg) ^ (d & 7);
        bfrag bv_ = *(const bfrag*)&Vt[cur][d * 64 + off * 8];
#pragma unroll
        for (int fm = 0; fm < 2; ++fm)
          o[fm][fn2] = mfma16(ap[fm], bv_, o[fm][fn2]);
      }
    }

    // write-late: V(t+1) regs -> Vt[nxt] (prev readers of Vt[nxt] finished
    // before last barrier; this iter's readers use Vt[cur])
    if (pre) {
#pragma unroll
      for (int i = 0; i < 4; ++i)
#pragma unroll
        for (int j2 = 0; j2 < 8; ++j2) {
          int d = w * 32 + i * 8 + j2;
          Vt[nxt][d * 64 + (((l >> 3) ^ (d & 7)) << 3) + (l & 7)] = vreg[i][j2];
        }
    }
    __syncthreads();  // drains vmcnt(0): K prefetch (issued a full iter ago) lands
  }

  // epilogue: O/l - V[row]; write vals2[b, c', h*128+d] as bf16
  const int b = bh >> 3, h = bh & 7;
#pragma unroll
  for (int fm = 0; fm < 2; ++fm) {
#pragma unroll
    for (int r = 0; r < 4; ++r) {
      int c1 = qr0 + fm * 16 + lg * 4 + r;
      float inv = 1.f / lst[fm][r];
      const u16* vrow = vp + (size_t)c1 * Dn;
      u16* orow = attout + ((size_t)(b * 1024 + c1) * 8 + h) * 128;
#pragma unroll
      for (int fn2 = 0; fn2 < 8; ++fn2) {
        int d = fn2 * 16 + lr;
        float val = o[fm][fn2][r] * inv - bf2f(vrow[d]);
        orow[d] = f2bf(val);
      }
    }
  }
}

// ---------- output GEMM: [16384][1024] @ [1024][128] + bias -> f32 ----------
__global__ void out_gemm(const u16* __restrict__ A, const u16* __restrict__ Bt,
                         const float* __restrict__ bias, float* __restrict__ out) {
  __shared__ u16 As[64 * 64];
  __shared__ u16 Bs[128 * 64];
  const int m0 = blockIdx.x * 64;
  const int tid = threadIdx.x, l = tid & 63, w = tid >> 6;
  const int lr = l & 15, lg = l >> 4;
  const int wr = w >> 1, wc = w & 1;
  f32x4 acc[2][4] = {};

  for (int kt = 0; kt < 1024; kt += 64) {
#pragma unroll
    for (int i = 0; i < 2; ++i) {
      int chb = (i * 4 + w) * 64;
      int ch = chb + l;
      int row = ch >> 3, scc = (ch & 7) ^ (row & 7);
      gload16(A + (size_t)(m0 + row) * 1024 + kt + scc * 8, &As[chb * 8]);
    }
#pragma unroll
    for (int i = 0; i < 4; ++i) {
      int chb = (i * 4 + w) * 64;
      int ch = chb + l;
      int row = ch >> 3, scc = (ch & 7) ^ (row & 7);
      gload16(Bt + (size_t)row * 1024 + kt + scc * 8, &Bs[chb * 8]);
    }
    __syncthreads();
#pragma unroll
    for (int kk = 0; kk < 2; ++kk) {
      bfrag af[2], bf_[4];
#pragma unroll
      for (int fm = 0; fm < 2; ++fm) {
        int row = wr * 32 + fm * 16 + lr;
        int off = (kk * 4 + lg) ^ (row & 7);
        af[fm] = *(const bfrag*)&As[row * 64 + off * 8];
      }
#pragma unroll
      for (int fn = 0; fn < 4; ++fn) {
        int row = wc * 64 + fn * 16 + lr;
        int off = (kk * 4 + lg) ^ (row & 7);
        bf_[fn] = *(const bfrag*)&Bs[row * 64 + off * 8];
      }
#pragma unroll
      for (int fm = 0; fm < 2; ++fm)
#pragma unroll
        for (int fn = 0; fn < 4; ++fn)
          acc[fm][fn] = mfma16(af[fm], bf_[fn], acc[fm][fn]);
    }
    __syncthreads();
  }
#pragma unroll
  for (int fm = 0; fm < 2; ++fm)
#pragma unroll
    for (int r = 0; r < 4; ++r) {
      int m = m0 + wr * 32 + fm * 16 + lg * 4 + r;
#pragma unroll
      for (int fn = 0; fn < 4; ++fn) {
        int j = wc * 64 + fn * 16 + lr;
        out[(size_t)m * 128 + j] = acc[fm][fn][r] + bias[j];
      }
    }
}

// ---------- launch ----------
extern "C" void kernel_launch(void* const* d_in, const int* in_sizes, int n_in,
                              void* d_out, int out_size, void* d_ws, size_t ws_size,
                              hipStream_t stream) {
  const float* x   = (const float*)d_in[0];
  const float* Wk  = (const float*)d_in[1];
  const float* bk_ = (const float*)d_in[2];
  const float* Wq  = (const float*)d_in[3];
  const float* bq_ = (const float*)d_in[4];
  const float* Wv  = (const float*)d_in[5];
  const float* bv_ = (const float*)d_in[6];
  const float* Ww0 = (const float*)d_in[7];
  const float* bw0 = (const float*)d_in[8];
  float* out = (float*)d_out;

  char* ws = (char*)d_ws;
  u16* xb   = (u16*)(ws + OFF_XB);
  u16* wt   = (u16*)(ws + OFF_WT);
  u16* w0t  = (u16*)(ws + OFF_W0T);
  u16* qpm  = (u16*)(ws + OFF_Q);
  u16* kpm  = (u16*)(ws + OFF_K);
  u16* vpm  = (u16*)(ws + OFF_V);
  u16* attb = (u16*)(ws + OFF_ATT);

  // prep: cast x, transpose+cast weights
  cvt_bf16<<<(M1 * Fn / 4 + 255) / 256, 256, 0, stream>>>(x, xb, M1 * Fn);
  dim3 tb(32, 8);
  transpose_cvt<<<dim3(32, 16), tb, 0, stream>>>(Wq, wt + 0 * 1024 * 512, 512, 1024);
  transpose_cvt<<<dim3(32, 16), tb, 0, stream>>>(Wk, wt + 1 * 1024 * 512, 512, 1024);
  transpose_cvt<<<dim3(32, 16), tb, 0, stream>>>(Wv, wt + 2 * 1024 * 512, 512, 1024);
  transpose_cvt<<<dim3(4, 32),  tb, 0, stream>>>(Ww0, w0t, 1024, 128);

  // projections -> permuted q/k/v (bf16)
  qkv_gemm<<<dim3(128, 8, 3), 256, 0, stream>>>(xb, wt, bq_, bk_, bv_, qpm, kpm, vpm);

  // fused attention (softmax - I folded as O = P@V - V), XCD-swizzled grid
  attn_kernel<<<dim3(1024), 256, 0, stream>>>(qpm, kpm, vpm, attb);

  // output projection (f32 out + bias)
  out_gemm<<<256, 256, 0, stream>>>(attb, w0t, bw0, out);
}

// Round 3
// 292.158 us; speedup vs baseline: 3.2301x; 3.2301x over previous
//
#include <hip/hip_runtime.h>
#include <hip/hip_bf16.h>
#include <cstdint>
#include <cstddef>

// ---------- types ----------
using u16 = unsigned short;
typedef __attribute__((ext_vector_type(4))) float f32x4;
typedef __attribute__((ext_vector_type(8))) unsigned short u16x8;
typedef __attribute__((ext_vector_type(4))) unsigned short u16x4;
typedef __bf16 bfrag __attribute__((ext_vector_type(8)));   // 8 bf16 = 4 VGPR MFMA operand

constexpr int Hn = 8, Cn = 1024, Dn = 128, Fn = 512, Bn = 16;
constexpr int M1 = Bn * Cn;  // 16384 rows of x / att_out

// workspace layout (bytes)
constexpr size_t OFF_XB  = 0;                                  // x bf16 [16384][512]
constexpr size_t SZ_XB   = (size_t)M1 * Fn * 2;                // 16 MiB
constexpr size_t OFF_WT  = OFF_XB + SZ_XB;                     // Wt bf16 [3][1024][512] (q,k,v)
constexpr size_t SZ_WT   = 3ull * 1024 * 512 * 2;              // 3 MiB
constexpr size_t OFF_W0T = OFF_WT + SZ_WT;                     // Ww0^T bf16 [128][1024]
constexpr size_t SZ_W0T  = 128ull * 1024 * 2;
constexpr size_t OFF_Q   = OFF_W0T + SZ_W0T;                   // q perm [16][8][1024][128] bf16
constexpr size_t SZ_P    = (size_t)Bn * Hn * Cn * Dn * 2;      // 32 MiB each
constexpr size_t OFF_K   = OFF_Q + SZ_P;
constexpr size_t OFF_V   = OFF_K + SZ_P;
constexpr size_t OFF_ATT = OFF_V + SZ_P;                       // vals2 bf16 [16384][1024]

// ---------- helpers ----------
__device__ __forceinline__ float bf2f(u16 u) {
  unsigned int x = ((unsigned int)u) << 16;
  return __builtin_bit_cast(float, x);
}
__device__ __forceinline__ u16 f2bf(float f) {
  unsigned int u = __builtin_bit_cast(unsigned int, f);
  u += 0x7fffu + ((u >> 16) & 1u);   // RNE
  return (u16)(u >> 16);
}
__device__ __forceinline__ f32x4 mfma16(bfrag a, bfrag b, f32x4 c) {
  return __builtin_amdgcn_mfma_f32_16x16x32_bf16(a, b, c, 0, 0, 0);
}
// async 16B global->LDS; lds base must be wave-uniform (lane*16 auto-offset)
__device__ __forceinline__ void gload16(const void* g, void* lds) {
  __builtin_amdgcn_global_load_lds(
      (const __attribute__((address_space(1))) unsigned int*)g,
      (__attribute__((address_space(3))) unsigned int*)lds, 16, 0, 0);
}

// ---------- prep kernels ----------
__global__ void cvt_bf16(const float* __restrict__ in, u16* __restrict__ out, int n) {
  int idx = (blockIdx.x * blockDim.x + threadIdx.x) * 4;
  if (idx < n) {
    float4 v = *(const float4*)(in + idx);
    u16x4 o;
    o.x = f2bf(v.x); o.y = f2bf(v.y); o.z = f2bf(v.z); o.w = f2bf(v.w);
    *(u16x4*)(out + idx) = o;
  }
}

// in [R][Cc] f32 -> out [Cc][R] bf16 ; block (32,8), grid (Cc/32, R/32)
__global__ void transpose_cvt(const float* __restrict__ in, u16* __restrict__ out,
                              int R, int Cc) {
  __shared__ float tile[32][33];
  int c0 = blockIdx.x * 32, r0 = blockIdx.y * 32;
  int tx = threadIdx.x, ty = threadIdx.y;
#pragma unroll
  for (int i = 0; i < 4; ++i)
    tile[ty + i * 8][tx] = in[(size_t)(r0 + ty + i * 8) * Cc + c0 + tx];
  __syncthreads();
#pragma unroll
  for (int i = 0; i < 4; ++i)
    out[(size_t)(c0 + ty + i * 8) * R + r0 + tx] = f2bf(tile[tx][ty + i * 8]);
}

// ---------- QKV projection GEMM ----------
__global__ void qkv_gemm(const u16* __restrict__ xb, const u16* __restrict__ wt,
                         const float* __restrict__ bq, const float* __restrict__ bk,
                         const float* __restrict__ bv,
                         u16* __restrict__ qout, u16* __restrict__ kout,
                         u16* __restrict__ vout) {
  __shared__ u16 As[128 * 64];
  __shared__ u16 Bs[128 * 64];
  const int m0 = blockIdx.x * 128;
  const int n0 = blockIdx.y * 128;
  const int p  = blockIdx.z;
  const u16* wp = wt + (size_t)p * 1024 * 512;
  const float* bias = (p == 0) ? bq : (p == 1) ? bk : bv;
  u16* outp = (p == 0) ? qout : (p == 1) ? kout : vout;

  const int tid = threadIdx.x, l = tid & 63, w = tid >> 6;
  const int lr = l & 15, lg = l >> 4;
  const int wr = w >> 1, wc = w & 1;

  f32x4 acc[4][4] = {};

  for (int kt = 0; kt < Fn; kt += 64) {
#pragma unroll
    for (int i = 0; i < 4; ++i) {
      int chb = (i * 4 + w) * 64;
      int ch = chb + l;
      int row = ch >> 3, scc = (ch & 7) ^ (row & 7);
      gload16(xb + (size_t)(m0 + row) * Fn + kt + scc * 8, &As[chb * 8]);
    }
#pragma unroll
    for (int i = 0; i < 4; ++i) {
      int chb = (i * 4 + w) * 64;
      int ch = chb + l;
      int row = ch >> 3, scc = (ch & 7) ^ (row & 7);
      gload16(wp + (size_t)(n0 + row) * Fn + kt + scc * 8, &Bs[chb * 8]);
    }
    __syncthreads();
#pragma unroll
    for (int kk = 0; kk < 2; ++kk) {
      bfrag af[4], bf_[4];
#pragma unroll
      for (int fm = 0; fm < 4; ++fm) {
        int row = wr * 64 + fm * 16 + lr;
        int off = (kk * 4 + lg) ^ (row & 7);
        af[fm] = *(const bfrag*)&As[row * 64 + off * 8];
      }
#pragma unroll
      for (int fn = 0; fn < 4; ++fn) {
        int row = wc * 64 + fn * 16 + lr;
        int off = (kk * 4 + lg) ^ (row & 7);
        bf_[fn] = *(const bfrag*)&Bs[row * 64 + off * 8];
      }
#pragma unroll
      for (int fm = 0; fm < 4; ++fm)
#pragma unroll
        for (int fn = 0; fn < 4; ++fn)
          acc[fm][fn] = mfma16(af[fm], bf_[fn], acc[fm][fn]);
    }
    __syncthreads();
  }

  // epilogue: perm write  (h'=c>>7, c'=(c&127)*8+(j>>7), d=j&127)
#pragma unroll
  for (int fm = 0; fm < 4; ++fm) {
#pragma unroll
    for (int r = 0; r < 4; ++r) {
      int m = m0 + wr * 64 + fm * 16 + lg * 4 + r;
      int b = m >> 10, c = m & 1023;
      int gh = c >> 7;
#pragma unroll
      for (int fn = 0; fn < 4; ++fn) {
        int j = n0 + wc * 64 + fn * 16 + lr;
        float v = acc[fm][fn][r] + bias[j];
        int ii = ((c & 127) << 3) | (j >> 7);
        int d = j & 127;
        size_t idx = (((size_t)(b * 8 + gh) * 1024 + ii) << 7) | d;
        outp[idx] = f2bf(v);
      }
    }
  }
}

// ---------- fused flash attention ----------
// O = softmax(QK^T/sqrt(D))@V - V.  2048 blocks (XCD-swizzled: XCD k owns
// heads 16k..16k+15), 4 waves/block, wave owns 16 q-rows (block = 64 q-rows).
// Single-buffered stage->barrier->compute->barrier; small per-wave state
// (~110 VGPR) so NOTHING spills; 40KB LDS -> 4 blocks/CU for TLP cover.
__global__ __launch_bounds__(256, 4)
void attn_kernel(const u16* __restrict__ qp_all, const u16* __restrict__ kp_all,
                 const u16* __restrict__ vp_all, u16* __restrict__ attout) {
  __shared__ u16 Ks[64 * 128];    // [kv][f] linear, source-preswizzled chunks
  __shared__ u16 Vt[128 * 64];    // V^T [d][kv], chunk-XOR swizzled
  __shared__ u16 Ps[4][16 * 64];  // per-wave P [q][kv], chunk-XOR swizzled

  const int bid = blockIdx.x;
  const int wg = (bid & 7) * 256 + (bid >> 3);
  const int bh = wg >> 4;
  const int qt = wg & 15;

  const int tid = threadIdx.x, l = tid & 63, w = tid >> 6;
  const int lr = l & 15, lg = l >> 4;

  const u16* qp = qp_all + (size_t)bh * (Cn * Dn);
  const u16* kp = kp_all + (size_t)bh * (Cn * Dn);
  const u16* vp = vp_all + (size_t)bh * (Cn * Dn);
  const int qr0 = qt * 64 + w * 16;

  // Q fragments in registers for the whole kernel (16 VGPRs)
  bfrag aq[4];
#pragma unroll
  for (int kk = 0; kk < 4; ++kk)
    aq[kk] = *(const bfrag*)(qp + (size_t)(qr0 + lr) * Dn + kk * 32 + lg * 8);

  f32x4 o[8] = {};
  float mst[4], lst[4];
#pragma unroll
  for (int r = 0; r < 4; ++r) { mst[r] = -1e30f; lst[r] = 0.f; }

  const float cl2 = 0.12751744f;  // log2(e)/sqrt(128): softmax in exp2 domain

  for (int t = 0; t < 16; ++t) {
    // stage K [64][128]: 1024 chunks of 16B, source pre-swizzled
#pragma unroll
    for (int i = 0; i < 4; ++i) {
      int chb = (i * 4 + w) * 64;
      int ch = chb + l;
      int row = ch >> 4, scc = (ch & 15) ^ (row & 7);
      gload16(kp + (size_t)(t * 64 + row) * Dn + scc * 8, &Ks[chb * 8]);
    }
    // stage V^T via regs (consumed immediately -> no long live range)
    {
      const u16* vr = vp + (size_t)(t * 64 + l) * Dn + w * 32;
#pragma unroll
      for (int i = 0; i < 4; ++i) {
        u16x8 vv = *(const u16x8*)(vr + i * 8);
#pragma unroll
        for (int j2 = 0; j2 < 8; ++j2) {
          int d = w * 32 + i * 8 + j2;
          Vt[d * 64 + (((l >> 3) ^ (d & 7)) << 3) + (l & 7)] = vv[j2];
        }
      }
    }
    __syncthreads();

    // S = Q K^T  (per wave: [16 q][64 kv])
    f32x4 s[4] = {};
#pragma unroll
    for (int kk = 0; kk < 4; ++kk) {
      bfrag bk_[4];
#pragma unroll
      for (int fn = 0; fn < 4; ++fn) {
        int row = fn * 16 + lr;
        int off = (kk * 4 + lg) ^ (row & 7);
        bk_[fn] = *(const bfrag*)&Ks[row * 128 + off * 8];
      }
#pragma unroll
      for (int fn = 0; fn < 4; ++fn)
        s[fn] = mfma16(aq[kk], bk_[fn], s[fn]);
    }

    // online softmax in exp2 domain (rows = lg*4+r, cols spread over 16 lanes)
#pragma unroll
    for (int r = 0; r < 4; ++r) {
      float mx = fmaxf(fmaxf(s[0][r], s[1][r]), fmaxf(s[2][r], s[3][r]));
#pragma unroll
      for (int mk = 1; mk < 16; mk <<= 1) mx = fmaxf(mx, __shfl_xor(mx, mk, 64));
      float mold = mst[r];
      float mnew = fmaxf(mold, mx * cl2);
      float alpha = exp2f(mold - mnew);
      mst[r] = mnew;
      float rs = 0.f;
#pragma unroll
      for (int fn = 0; fn < 4; ++fn) {
        float pv = exp2f(fmaf(s[fn][r], cl2, -mnew));
        s[fn][r] = pv;
        rs += pv;
      }
#pragma unroll
      for (int mk = 1; mk < 16; mk <<= 1) rs += __shfl_xor(rs, mk, 64);
      lst[r] = lst[r] * alpha + rs;
#pragma unroll
      for (int fn2 = 0; fn2 < 8; ++fn2) o[fn2][r] *= alpha;
    }

    // P -> per-wave LDS (swizzled); same-wave RAW, no barrier needed
#pragma unroll
    for (int fn = 0; fn < 4; ++fn)
#pragma unroll
      for (int r = 0; r < 4; ++r) {
        int q = lg * 4 + r;
        int col = fn * 16 + lr;
        Ps[w][q * 64 + (((col >> 3) ^ (q & 7)) << 3) + (col & 7)] = f2bf(s[fn][r]);
      }

    // PV
#pragma unroll
    for (int kk = 0; kk < 2; ++kk) {
      int qq = lr;
      int offp = (kk * 4 + lg) ^ (qq & 7);
      bfrag ap = *(const bfrag*)&Ps[w][qq * 64 + offp * 8];
#pragma unroll
      for (int fn2 = 0; fn2 < 8; ++fn2) {
        int d = fn2 * 16 + lr;
        int offv = (kk * 4 + lg) ^ (d & 7);
        bfrag bv_ = *(const bfrag*)&Vt[d * 64 + offv * 8];
        o[fn2] = mfma16(ap, bv_, o[fn2]);
      }
    }
    __syncthreads();  // protect Ks/Vt before next iteration's staging
  }

  // epilogue: O/l - V[row]; write vals2[b, c', h*128+d] as bf16
  const int b = bh >> 3, h = bh & 7;
#pragma unroll
  for (int r = 0; r < 4; ++r) {
    int c1 = qr0 + lg * 4 + r;
    float inv = 1.f / lst[r];
    const u16* vrow = vp + (size_t)c1 * Dn;
    u16* orow = attout + ((size_t)(b * 1024 + c1) * 8 + h) * 128;
#pragma unroll
    for (int fn2 = 0; fn2 < 8; ++fn2) {
      int d = fn2 * 16 + lr;
      float val = o[fn2][r] * inv - bf2f(vrow[d]);
      orow[d] = f2bf(val);
    }
  }
}

// ---------- output GEMM: [16384][1024] @ [1024][128] + bias -> f32 ----------
__global__ void out_gemm(const u16* __restrict__ A, const u16* __restrict__ Bt,
                         const float* __restrict__ bias, float* __restrict__ out) {
  __shared__ u16 As[64 * 64];
  __shared__ u16 Bs[128 * 64];
  const int m0 = blockIdx.x * 64;
  const int tid = threadIdx.x, l = tid & 63, w = tid >> 6;
  const int lr = l & 15, lg = l >> 4;
  const int wr = w >> 1, wc = w & 1;
  f32x4 acc[2][4] = {};

  for (int kt = 0; kt < 1024; kt += 64) {
#pragma unroll
    for (int i = 0; i < 2; ++i) {
      int chb = (i * 4 + w) * 64;
      int ch = chb + l;
      int row = ch >> 3, scc = (ch & 7) ^ (row & 7);
      gload16(A + (size_t)(m0 + row) * 1024 + kt + scc * 8, &As[chb * 8]);
    }
#pragma unroll
    for (int i = 0; i < 4; ++i) {
      int chb = (i * 4 + w) * 64;
      int ch = chb + l;
      int row = ch >> 3, scc = (ch & 7) ^ (row & 7);
      gload16(Bt + (size_t)row * 1024 + kt + scc * 8, &Bs[chb * 8]);
    }
    __syncthreads();
#pragma unroll
    for (int kk = 0; kk < 2; ++kk) {
      bfrag af[2], bf_[4];
#pragma unroll
      for (int fm = 0; fm < 2; ++fm) {
        int row = wr * 32 + fm * 16 + lr;
        int off = (kk * 4 + lg) ^ (row & 7);
        af[fm] = *(const bfrag*)&As[row * 64 + off * 8];
      }
#pragma unroll
      for (int fn = 0; fn < 4; ++fn) {
        int row = wc * 64 + fn * 16 + lr;
        int off = (kk * 4 + lg) ^ (row & 7);
        bf_[fn] = *(const bfrag*)&Bs[row * 64 + off * 8];
      }
#pragma unroll
      for (int fm = 0; fm < 2; ++fm)
#pragma unroll
        for (int fn = 0; fn < 4; ++fn)
          acc[fm][fn] = mfma16(af[fm], bf_[fn], acc[fm][fn]);
    }
    __syncthreads();
  }
#pragma unroll
  for (int fm = 0; fm < 2; ++fm)
#pragma unroll
    for (int r = 0; r < 4; ++r) {
      int m = m0 + wr * 32 + fm * 16 + lg * 4 + r;
#pragma unroll
      for (int fn = 0; fn < 4; ++fn) {
        int j = wc * 64 + fn * 16 + lr;
        out[(size_t)m * 128 + j] = acc[fm][fn][r] + bias[j];
      }
    }
}

// ---------- launch ----------
extern "C" void kernel_launch(void* const* d_in, const int* in_sizes, int n_in,
                              void* d_out, int out_size, void* d_ws, size_t ws_size,
                              hipStream_t stream) {
  const float* x   = (const float*)d_in[0];
  const float* Wk  = (const float*)d_in[1];
  const float* bk_ = (const float*)d_in[2];
  const float* Wq  = (const float*)d_in[3];
  const float* bq_ = (const float*)d_in[4];
  const float* Wv  = (const float*)d_in[5];
  const float* bv_ = (const float*)d_in[6];
  const float* Ww0 = (const float*)d_in[7];
  const float* bw0 = (const float*)d_in[8];
  float* out = (float*)d_out;

  char* ws = (char*)d_ws;
  u16* xb   = (u16*)(ws + OFF_XB);
  u16* wt   = (u16*)(ws + OFF_WT);
  u16* w0t  = (u16*)(ws + OFF_W0T);
  u16* qpm  = (u16*)(ws + OFF_Q);
  u16* kpm  = (u16*)(ws + OFF_K);
  u16* vpm  = (u16*)(ws + OFF_V);
  u16* attb = (u16*)(ws + OFF_ATT);

  // prep: cast x, transpose+cast weights
  cvt_bf16<<<(M1 * Fn / 4 + 255) / 256, 256, 0, stream>>>(x, xb, M1 * Fn);
  dim3 tb(32, 8);
  transpose_cvt<<<dim3(32, 16), tb, 0, stream>>>(Wq, wt + 0 * 1024 * 512, 512, 1024);
  transpose_cvt<<<dim3(32, 16), tb, 0, stream>>>(Wk, wt + 1 * 1024 * 512, 512, 1024);
  transpose_cvt<<<dim3(32, 16), tb, 0, stream>>>(Wv, wt + 2 * 1024 * 512, 512, 1024);
  transpose_cvt<<<dim3(4, 32),  tb, 0, stream>>>(Ww0, w0t, 1024, 128);

  // projections -> permuted q/k/v (bf16)
  qkv_gemm<<<dim3(128, 8, 3), 256, 0, stream>>>(xb, wt, bq_, bk_, bv_, qpm, kpm, vpm);

  // fused attention (softmax - I folded as O = P@V - V), XCD-swizzled grid
  attn_kernel<<<dim3(2048), 256, 0, stream>>>(qpm, kpm, vpm, attb);

  // output projection (f32 out + bias)
  out_gemm<<<256, 256, 0, stream>>>(attb, w0t, bw0, out);
}

// Round 4
// 242.025 us; speedup vs baseline: 3.8991x; 1.2071x over previous
//
#include <hip/hip_runtime.h>
#include <hip/hip_bf16.h>
#include <cstdint>
#include <cstddef>

// ---------- types ----------
using u16 = unsigned short;
typedef __attribute__((ext_vector_type(4))) float f32x4;
typedef __attribute__((ext_vector_type(8))) unsigned short u16x8;
typedef __attribute__((ext_vector_type(4))) unsigned short u16x4;
typedef __attribute__((ext_vector_type(2))) unsigned int u32x2;
typedef __bf16 bfrag __attribute__((ext_vector_type(8)));   // 8 bf16 = 4 VGPR MFMA operand

constexpr int Hn = 8, Cn = 1024, Dn = 128, Fn = 512, Bn = 16;
constexpr int M1 = Bn * Cn;  // 16384 rows of x / att_out

// workspace layout (bytes)
constexpr size_t OFF_XB  = 0;                                  // x bf16 [16384][512]
constexpr size_t SZ_XB   = (size_t)M1 * Fn * 2;                // 16 MiB
constexpr size_t OFF_WT  = OFF_XB + SZ_XB;                     // Wt bf16 [3][1024][512] (q,k,v)
constexpr size_t SZ_WT   = 3ull * 1024 * 512 * 2;              // 3 MiB
constexpr size_t OFF_W0T = OFF_WT + SZ_WT;                     // Ww0^T bf16 [128][1024]
constexpr size_t SZ_W0T  = 128ull * 1024 * 2;
constexpr size_t OFF_Q   = OFF_W0T + SZ_W0T;                   // q perm [16][8][1024][128] bf16
constexpr size_t SZ_P    = (size_t)Bn * Hn * Cn * Dn * 2;      // 32 MiB each
constexpr size_t OFF_K   = OFF_Q + SZ_P;
constexpr size_t OFF_V   = OFF_K + SZ_P;
constexpr size_t OFF_ATT = OFF_V + SZ_P;                       // vals2 bf16 [16384][1024]

// ---------- helpers ----------
__device__ __forceinline__ float bf2f(u16 u) {
  unsigned int x = ((unsigned int)u) << 16;
  return __builtin_bit_cast(float, x);
}
__device__ __forceinline__ u16 f2bf(float f) {
  unsigned int u = __builtin_bit_cast(unsigned int, f);
  u += 0x7fffu + ((u >> 16) & 1u);   // RNE
  return (u16)(u >> 16);
}
__device__ __forceinline__ unsigned pack2bf(float a, float b) {
  return (unsigned)f2bf(a) | ((unsigned)f2bf(b) << 16);
}
__device__ __forceinline__ f32x4 mfma16(bfrag a, bfrag b, f32x4 c) {
  return __builtin_amdgcn_mfma_f32_16x16x32_bf16(a, b, c, 0, 0, 0);
}
// async 16B global->LDS; lds base must be wave-uniform (lane*16 auto-offset)
__device__ __forceinline__ void gload16(const void* g, void* lds) {
  __builtin_amdgcn_global_load_lds(
      (const __attribute__((address_space(1))) unsigned int*)g,
      (__attribute__((address_space(3))) unsigned int*)lds, 16, 0, 0);
}

// ---------- prep kernels ----------
__global__ void cvt_bf16(const float* __restrict__ in, u16* __restrict__ out, int n) {
  int idx = (blockIdx.x * blockDim.x + threadIdx.x) * 4;
  if (idx < n) {
    float4 v = *(const float4*)(in + idx);
    u16x4 o;
    o.x = f2bf(v.x); o.y = f2bf(v.y); o.z = f2bf(v.z); o.w = f2bf(v.w);
    *(u16x4*)(out + idx) = o;
  }
}

// in [R][Cc] f32 -> out [Cc][R] bf16 ; block (32,8), grid (Cc/32, R/32)
__global__ void transpose_cvt(const float* __restrict__ in, u16* __restrict__ out,
                              int R, int Cc) {
  __shared__ float tile[32][33];
  int c0 = blockIdx.x * 32, r0 = blockIdx.y * 32;
  int tx = threadIdx.x, ty = threadIdx.y;
#pragma unroll
  for (int i = 0; i < 4; ++i)
    tile[ty + i * 8][tx] = in[(size_t)(r0 + ty + i * 8) * Cc + c0 + tx];
  __syncthreads();
#pragma unroll
  for (int i = 0; i < 4; ++i)
    out[(size_t)(c0 + ty + i * 8) * R + r0 + tx] = f2bf(tile[tx][ty + i * 8]);
}

// ---------- QKV projection GEMM ----------
// NOTE: Q output (p==0) is pre-scaled by log2(e)/sqrt(D) so attention's
// softmax runs directly in the exp2 domain with no per-score multiply.
__global__ void qkv_gemm(const u16* __restrict__ xb, const u16* __restrict__ wt,
                         const float* __restrict__ bq, const float* __restrict__ bk,
                         const float* __restrict__ bv,
                         u16* __restrict__ qout, u16* __restrict__ kout,
                         u16* __restrict__ vout) {
  __shared__ u16 As[128 * 64];
  __shared__ u16 Bs[128 * 64];
  const int m0 = blockIdx.x * 128;
  const int n0 = blockIdx.y * 128;
  const int p  = blockIdx.z;
  const u16* wp = wt + (size_t)p * 1024 * 512;
  const float* bias = (p == 0) ? bq : (p == 1) ? bk : bv;
  u16* outp = (p == 0) ? qout : (p == 1) ? kout : vout;
  const float osc = (p == 0) ? 0.12751744116389548f : 1.0f;  // log2(e)/sqrt(128)

  const int tid = threadIdx.x, l = tid & 63, w = tid >> 6;
  const int lr = l & 15, lg = l >> 4;
  const int wr = w >> 1, wc = w & 1;

  f32x4 acc[4][4] = {};

  for (int kt = 0; kt < Fn; kt += 64) {
#pragma unroll
    for (int i = 0; i < 4; ++i) {
      int chb = (i * 4 + w) * 64;
      int ch = chb + l;
      int row = ch >> 3, scc = (ch & 7) ^ (row & 7);
      gload16(xb + (size_t)(m0 + row) * Fn + kt + scc * 8, &As[chb * 8]);
    }
#pragma unroll
    for (int i = 0; i < 4; ++i) {
      int chb = (i * 4 + w) * 64;
      int ch = chb + l;
      int row = ch >> 3, scc = (ch & 7) ^ (row & 7);
      gload16(wp + (size_t)(n0 + row) * Fn + kt + scc * 8, &Bs[chb * 8]);
    }
    __syncthreads();
#pragma unroll
    for (int kk = 0; kk < 2; ++kk) {
      bfrag af[4], bf_[4];
#pragma unroll
      for (int fm = 0; fm < 4; ++fm) {
        int row = wr * 64 + fm * 16 + lr;
        int off = (kk * 4 + lg) ^ (row & 7);
        af[fm] = *(const bfrag*)&As[row * 64 + off * 8];
      }
#pragma unroll
      for (int fn = 0; fn < 4; ++fn) {
        int row = wc * 64 + fn * 16 + lr;
        int off = (kk * 4 + lg) ^ (row & 7);
        bf_[fn] = *(const bfrag*)&Bs[row * 64 + off * 8];
      }
#pragma unroll
      for (int fm = 0; fm < 4; ++fm)
#pragma unroll
        for (int fn = 0; fn < 4; ++fn)
          acc[fm][fn] = mfma16(af[fm], bf_[fn], acc[fm][fn]);
    }
    __syncthreads();
  }

  // epilogue: perm write  (h'=c>>7, c'=(c&127)*8+(j>>7), d=j&127)
#pragma unroll
  for (int fm = 0; fm < 4; ++fm) {
#pragma unroll
    for (int r = 0; r < 4; ++r) {
      int m = m0 + wr * 64 + fm * 16 + lg * 4 + r;
      int b = m >> 10, c = m & 1023;
      int gh = c >> 7;
#pragma unroll
      for (int fn = 0; fn < 4; ++fn) {
        int j = n0 + wc * 64 + fn * 16 + lr;
        float v = (acc[fm][fn][r] + bias[j]) * osc;
        int ii = ((c & 127) << 3) | (j >> 7);
        int d = j & 127;
        size_t idx = (((size_t)(b * 8 + gh) * 1024 + ii) << 7) | d;
        outp[idx] = f2bf(v);
      }
    }
  }
}

// ---------- fused flash attention ----------
// O = softmax(QK^T/sqrt(D))@V - V.  2048 blocks (XCD-swizzled), 4 waves,
// wave owns 16 q-rows.  SWAPPED QK^T (S^T = mfma(K,Q)): each lane's 16
// S-values all belong to q-row (lane&15) -> softmax is lane-local trees +
// 2 shfl_xor steps (vs 32 butterfly shuffles).  Q pre-scaled by log2e/sqrt(D).
__global__ __launch_bounds__(256, 4)
void attn_kernel(const u16* __restrict__ qp_all, const u16* __restrict__ kp_all,
                 const u16* __restrict__ vp_all, u16* __restrict__ attout) {
  __shared__ u16 Ks[64 * 128];    // [kv][f] linear, source-preswizzled chunks
  __shared__ u16 Vt[128 * 64];    // V^T [d][kv], chunk-XOR swizzled
  __shared__ u16 Ps[4][16 * 64];  // per-wave P [q][kv], chunk-XOR swizzled

  const int bid = blockIdx.x;
  const int wg = (bid & 7) * 256 + (bid >> 3);
  const int bh = wg >> 4;
  const int qt = wg & 15;

  const int tid = threadIdx.x, l = tid & 63, w = tid >> 6;
  const int lr = l & 15, lg = l >> 4;

  const u16* qp = qp_all + (size_t)bh * (Cn * Dn);
  const u16* kp = kp_all + (size_t)bh * (Cn * Dn);
  const u16* vp = vp_all + (size_t)bh * (Cn * Dn);
  const int qr0 = qt * 64 + w * 16;

  // Q fragments (B-operand: lane j = q-col = lr, k-slice lg*8) -- same loads
  bfrag aq[4];
#pragma unroll
  for (int kk = 0; kk < 4; ++kk)
    aq[kk] = *(const bfrag*)(qp + (size_t)(qr0 + lr) * Dn + kk * 32 + lg * 8);

  f32x4 o[8] = {};
  float mst = -1e30f, lst = 0.f;  // scalar per-lane state (row q = lr)

  for (int t = 0; t < 16; ++t) {
    // stage K [64][128]: 1024 chunks of 16B, source pre-swizzled
#pragma unroll
    for (int i = 0; i < 4; ++i) {
      int chb = (i * 4 + w) * 64;
      int ch = chb + l;
      int row = ch >> 4, scc = (ch & 15) ^ (row & 7);
      gload16(kp + (size_t)(t * 64 + row) * Dn + scc * 8, &Ks[chb * 8]);
    }
    // stage V^T via regs (consumed immediately -> no long live range)
    {
      const u16* vr = vp + (size_t)(t * 64 + l) * Dn + w * 32;
#pragma unroll
      for (int i = 0; i < 4; ++i) {
        u16x8 vv = *(const u16x8*)(vr + i * 8);
#pragma unroll
        for (int j2 = 0; j2 < 8; ++j2) {
          int d = w * 32 + i * 8 + j2;
          Vt[d * 64 + (((l >> 3) ^ (d & 7)) << 3) + (l & 7)] = vv[j2];
        }
      }
    }
    __syncthreads();

    // S^T = K Q^T  (per wave: [64 kv][16 q]; lane holds col q=lr,
    // kv = fn*16 + lg*4 + r)
    f32x4 s[4] = {};
#pragma unroll
    for (int kk = 0; kk < 4; ++kk) {
      bfrag bk_[4];
#pragma unroll
      for (int fn = 0; fn < 4; ++fn) {
        int row = fn * 16 + lr;
        int off = (kk * 4 + lg) ^ (row & 7);
        bk_[fn] = *(const bfrag*)&Ks[row * 128 + off * 8];
      }
#pragma unroll
      for (int fn = 0; fn < 4; ++fn)
        s[fn] = mfma16(bk_[fn], aq[kk], s[fn]);   // SWAPPED: A=K, B=Q
    }

    // lane-local online softmax for q-row lr (already log2-scaled via Q)
    float mx = fmaxf(fmaxf(fmaxf(s[0][0], s[0][1]), fmaxf(s[0][2], s[0][3])),
                     fmaxf(fmaxf(s[1][0], s[1][1]), fmaxf(s[1][2], s[1][3])));
    mx = fmaxf(mx, fmaxf(fmaxf(fmaxf(s[2][0], s[2][1]), fmaxf(s[2][2], s[2][3])),
                         fmaxf(fmaxf(s[3][0], s[3][1]), fmaxf(s[3][2], s[3][3]))));
    mx = fmaxf(mx, __shfl_xor(mx, 16, 64));
    mx = fmaxf(mx, __shfl_xor(mx, 32, 64));
    float mnew = fmaxf(mst, mx);
    float alpha = exp2f(mst - mnew);
    mst = mnew;
    float rs = 0.f;
#pragma unroll
    for (int fn = 0; fn < 4; ++fn)
#pragma unroll
      for (int r = 0; r < 4; ++r) {
        float pv = exp2f(s[fn][r] - mnew);
        s[fn][r] = pv;
        rs += pv;
      }
    rs += __shfl_xor(rs, 16, 64);
    rs += __shfl_xor(rs, 32, 64);
    lst = lst * alpha + rs;

    // broadcast alpha to the o-accumulator rows (o rows are q = 4*lg + r)
    float arow[4];
#pragma unroll
    for (int r = 0; r < 4; ++r) arow[r] = __shfl(alpha, 4 * lg + r, 64);
#pragma unroll
    for (int fn2 = 0; fn2 < 8; ++fn2)
#pragma unroll
      for (int r = 0; r < 4; ++r) o[fn2][r] *= arow[r];

    // P[q=lr][kv] -> per-wave LDS as 4x ds_write_b64 (packed bf16 pairs)
#pragma unroll
    for (int fn = 0; fn < 4; ++fn) {
      u32x2 pv2;
      pv2.x = pack2bf(s[fn][0], s[fn][1]);
      pv2.y = pack2bf(s[fn][2], s[fn][3]);
      int c = 2 * fn + (lg >> 1);
      int cp = c ^ (lr & 7);
      *(u32x2*)&Ps[w][lr * 64 + cp * 8 + (lg & 1) * 4] = pv2;
    }

    // PV: O[q][d] += P[q][kv] V[kv][d]
#pragma unroll
    for (int kk = 0; kk < 2; ++kk) {
      int offp = (kk * 4 + lg) ^ (lr & 7);
      bfrag ap = *(const bfrag*)&Ps[w][lr * 64 + offp * 8];
#pragma unroll
      for (int fn2 = 0; fn2 < 8; ++fn2) {
        int d = fn2 * 16 + lr;
        int offv = (kk * 4 + lg) ^ (d & 7);
        bfrag bv_ = *(const bfrag*)&Vt[d * 64 + offv * 8];
        o[fn2] = mfma16(ap, bv_, o[fn2]);
      }
    }
    __syncthreads();  // protect Ks/Vt before next iteration's staging
  }

  // epilogue: O/l - V[row]; write vals2[b, c', h*128+d] as bf16
  float linv[4];
#pragma unroll
  for (int r = 0; r < 4; ++r) linv[r] = 1.f / __shfl(lst, 4 * lg + r, 64);

  const int b = bh >> 3, h = bh & 7;
#pragma unroll
  for (int r = 0; r < 4; ++r) {
    int c1 = qr0 + lg * 4 + r;
    const u16* vrow = vp + (size_t)c1 * Dn;
    u16* orow = attout + ((size_t)(b * 1024 + c1) * 8 + h) * 128;
#pragma unroll
    for (int fn2 = 0; fn2 < 8; ++fn2) {
      int d = fn2 * 16 + lr;
      float val = o[fn2][r] * linv[r] - bf2f(vrow[d]);
      orow[d] = f2bf(val);
    }
  }
}

// ---------- output GEMM: [16384][1024] @ [1024][128] + bias -> f32 ----------
__global__ void out_gemm(const u16* __restrict__ A, const u16* __restrict__ Bt,
                         const float* __restrict__ bias, float* __restrict__ out) {
  __shared__ u16 As[64 * 64];
  __shared__ u16 Bs[128 * 64];
  const int m0 = blockIdx.x * 64;
  const int tid = threadIdx.x, l = tid & 63, w = tid >> 6;
  const int lr = l & 15, lg = l >> 4;
  const int wr = w >> 1, wc = w & 1;
  f32x4 acc[2][4] = {};

  for (int kt = 0; kt < 1024; kt += 64) {
#pragma unroll
    for (int i = 0; i < 2; ++i) {
      int chb = (i * 4 + w) * 64;
      int ch = chb + l;
      int row = ch >> 3, scc = (ch & 7) ^ (row & 7);
      gload16(A + (size_t)(m0 + row) * 1024 + kt + scc * 8, &As[chb * 8]);
    }
#pragma unroll
    for (int i = 0; i < 4; ++i) {
      int chb = (i * 4 + w) * 64;
      int ch = chb + l;
      int row = ch >> 3, scc = (ch & 7) ^ (row & 7);
      gload16(Bt + (size_t)row * 1024 + kt + scc * 8, &Bs[chb * 8]);
    }
    __syncthreads();
#pragma unroll
    for (int kk = 0; kk < 2; ++kk) {
      bfrag af[2], bf_[4];
#pragma unroll
      for (int fm = 0; fm < 2; ++fm) {
        int row = wr * 32 + fm * 16 + lr;
        int off = (kk * 4 + lg) ^ (row & 7);
        af[fm] = *(const bfrag*)&As[row * 64 + off * 8];
      }
#pragma unroll
      for (int fn = 0; fn < 4; ++fn) {
        int row = wc * 64 + fn * 16 + lr;
        int off = (kk * 4 + lg) ^ (row & 7);
        bf_[fn] = *(const bfrag*)&Bs[row * 64 + off * 8];
      }
#pragma unroll
      for (int fm = 0; fm < 2; ++fm)
#pragma unroll
        for (int fn = 0; fn < 4; ++fn)
          acc[fm][fn] = mfma16(af[fm], bf_[fn], acc[fm][fn]);
    }
    __syncthreads();
  }
#pragma unroll
  for (int fm = 0; fm < 2; ++fm)
#pragma unroll
    for (int r = 0; r < 4; ++r) {
      int m = m0 + wr * 32 + fm * 16 + lg * 4 + r;
#pragma unroll
      for (int fn = 0; fn < 4; ++fn) {
        int j = wc * 64 + fn * 16 + lr;
        out[(size_t)m * 128 + j] = acc[fm][fn][r] + bias[j];
      }
    }
}

// ---------- launch ----------
extern "C" void kernel_launch(void* const* d_in, const int* in_sizes, int n_in,
                              void* d_out, int out_size, void* d_ws, size_t ws_size,
                              hipStream_t stream) {
  const float* x   = (const float*)d_in[0];
  const float* Wk  = (const float*)d_in[1];
  const float* bk_ = (const float*)d_in[2];
  const float* Wq  = (const float*)d_in[3];
  const float* bq_ = (const float*)d_in[4];
  const float* Wv  = (const float*)d_in[5];
  const float* bv_ = (const float*)d_in[6];
  const float* Ww0 = (const float*)d_in[7];
  const float* bw0 = (const float*)d_in[8];
  float* out = (float*)d_out;

  char* ws = (char*)d_ws;
  u16* xb   = (u16*)(ws + OFF_XB);
  u16* wt   = (u16*)(ws + OFF_WT);
  u16* w0t  = (u16*)(ws + OFF_W0T);
  u16* qpm  = (u16*)(ws + OFF_Q);
  u16* kpm  = (u16*)(ws + OFF_K);
  u16* vpm  = (u16*)(ws + OFF_V);
  u16* attb = (u16*)(ws + OFF_ATT);

  // prep: cast x, transpose+cast weights
  cvt_bf16<<<(M1 * Fn / 4 + 255) / 256, 256, 0, stream>>>(x, xb, M1 * Fn);
  dim3 tb(32, 8);
  transpose_cvt<<<dim3(32, 16), tb, 0, stream>>>(Wq, wt + 0 * 1024 * 512, 512, 1024);
  transpose_cvt<<<dim3(32, 16), tb, 0, stream>>>(Wk, wt + 1 * 1024 * 512, 512, 1024);
  transpose_cvt<<<dim3(32, 16), tb, 0, stream>>>(Wv, wt + 2 * 1024 * 512, 512, 1024);
  transpose_cvt<<<dim3(4, 32),  tb, 0, stream>>>(Ww0, w0t, 1024, 128);

  // projections -> permuted q/k/v (bf16); Q pre-scaled by log2e/sqrt(D)
  qkv_gemm<<<dim3(128, 8, 3), 256, 0, stream>>>(xb, wt, bq_, bk_, bv_, qpm, kpm, vpm);

  // fused attention (softmax - I folded as O = P@V - V), XCD-swizzled grid
  attn_kernel<<<dim3(2048), 256, 0, stream>>>(qpm, kpm, vpm, attb);

  // output projection (f32 out + bias)
  out_gemm<<<256, 256, 0, stream>>>(attb, w0t, bw0, out);
}

// Round 5
// 234.534 us; speedup vs baseline: 4.0237x; 1.0319x over previous
//
#include <hip/hip_runtime.h>
#include <hip/hip_bf16.h>
#include <cstdint>
#include <cstddef>

// ---------- types ----------
using u16 = unsigned short;
typedef __attribute__((ext_vector_type(4))) float f32x4;
typedef __attribute__((ext_vector_type(16))) float f32x16;
typedef __attribute__((ext_vector_type(8))) unsigned short u16x8;
typedef __attribute__((ext_vector_type(4))) unsigned short u16x4;
typedef __attribute__((ext_vector_type(4))) unsigned int u32x4;
typedef __bf16 bfrag __attribute__((ext_vector_type(8)));   // 8 bf16 = 4 VGPR MFMA operand

constexpr int Hn = 8, Cn = 1024, Dn = 128, Fn = 512, Bn = 16;
constexpr int M1 = Bn * Cn;  // 16384 rows of x / att_out

// workspace layout (bytes)
constexpr size_t OFF_XB  = 0;                                  // x bf16 [16384][512]
constexpr size_t SZ_XB   = (size_t)M1 * Fn * 2;                // 16 MiB
constexpr size_t OFF_WT  = OFF_XB + SZ_XB;                     // Wt bf16 [3][1024][512] (q,k,v)
constexpr size_t SZ_WT   = 3ull * 1024 * 512 * 2;              // 3 MiB
constexpr size_t OFF_W0T = OFF_WT + SZ_WT;                     // Ww0^T bf16 [128][1024]
constexpr size_t SZ_W0T  = 128ull * 1024 * 2;
constexpr size_t OFF_Q   = OFF_W0T + SZ_W0T;                   // q perm [16][8][1024][128] bf16
constexpr size_t SZ_P    = (size_t)Bn * Hn * Cn * Dn * 2;      // 32 MiB each
constexpr size_t OFF_K   = OFF_Q + SZ_P;
constexpr size_t OFF_V   = OFF_K + SZ_P;
constexpr size_t OFF_ATT = OFF_V + SZ_P;                       // vals2 bf16 [16384][1024]

// ---------- helpers ----------
__device__ __forceinline__ float bf2f(u16 u) {
  unsigned int x = ((unsigned int)u) << 16;
  return __builtin_bit_cast(float, x);
}
__device__ __forceinline__ u16 f2bf(float f) {
  unsigned int u = __builtin_bit_cast(unsigned int, f);
  u += 0x7fffu + ((u >> 16) & 1u);   // RNE
  return (u16)(u >> 16);
}
__device__ __forceinline__ f32x4 mfma16(bfrag a, bfrag b, f32x4 c) {
  return __builtin_amdgcn_mfma_f32_16x16x32_bf16(a, b, c, 0, 0, 0);
}
__device__ __forceinline__ f32x16 mfma32(bfrag a, bfrag b, f32x16 c) {
  return __builtin_amdgcn_mfma_f32_32x32x16_bf16(a, b, c, 0, 0, 0);
}
// async 16B global->LDS; lds base must be wave-uniform (lane*16 auto-offset)
__device__ __forceinline__ void gload16(const void* g, void* lds) {
  __builtin_amdgcn_global_load_lds(
      (const __attribute__((address_space(1))) unsigned int*)g,
      (__attribute__((address_space(3))) unsigned int*)lds, 16, 0, 0);
}
__device__ __forceinline__ unsigned cvtpk(float lo, float hi) {
  unsigned r;
  asm("v_cvt_pk_bf16_f32 %0, %1, %2" : "=v"(r) : "v"(lo), "v"(hi));
  return r;
}

// ---------- prep kernels ----------
__global__ void cvt_bf16(const float* __restrict__ in, u16* __restrict__ out, int n) {
  int idx = (blockIdx.x * blockDim.x + threadIdx.x) * 4;
  if (idx < n) {
    float4 v = *(const float4*)(in + idx);
    u16x4 o;
    o.x = f2bf(v.x); o.y = f2bf(v.y); o.z = f2bf(v.z); o.w = f2bf(v.w);
    *(u16x4*)(out + idx) = o;
  }
}

// in [R][Cc] f32 -> out [Cc][R] bf16 ; block (32,8), grid (Cc/32, R/32)
__global__ void transpose_cvt(const float* __restrict__ in, u16* __restrict__ out,
                              int R, int Cc) {
  __shared__ float tile[32][33];
  int c0 = blockIdx.x * 32, r0 = blockIdx.y * 32;
  int tx = threadIdx.x, ty = threadIdx.y;
#pragma unroll
  for (int i = 0; i < 4; ++i)
    tile[ty + i * 8][tx] = in[(size_t)(r0 + ty + i * 8) * Cc + c0 + tx];
  __syncthreads();
#pragma unroll
  for (int i = 0; i < 4; ++i)
    out[(size_t)(c0 + ty + i * 8) * R + r0 + tx] = f2bf(tile[tx][ty + i * 8]);
}

// ---------- QKV projection GEMM ----------
// NOTE: Q output (p==0) is pre-scaled by log2(e)/sqrt(D) so attention's
// softmax runs directly in the exp2 domain with no per-score multiply.
__global__ void qkv_gemm(const u16* __restrict__ xb, const u16* __restrict__ wt,
                         const float* __restrict__ bq, const float* __restrict__ bk,
                         const float* __restrict__ bv,
                         u16* __restrict__ qout, u16* __restrict__ kout,
                         u16* __restrict__ vout) {
  __shared__ u16 As[128 * 64];
  __shared__ u16 Bs[128 * 64];
  const int m0 = blockIdx.x * 128;
  const int n0 = blockIdx.y * 128;
  const int p  = blockIdx.z;
  const u16* wp = wt + (size_t)p * 1024 * 512;
  const float* bias = (p == 0) ? bq : (p == 1) ? bk : bv;
  u16* outp = (p == 0) ? qout : (p == 1) ? kout : vout;
  const float osc = (p == 0) ? 0.12751744116389548f : 1.0f;  // log2(e)/sqrt(128)

  const int tid = threadIdx.x, l = tid & 63, w = tid >> 6;
  const int lr = l & 15, lg = l >> 4;
  const int wr = w >> 1, wc = w & 1;

  f32x4 acc[4][4] = {};

  for (int kt = 0; kt < Fn; kt += 64) {
#pragma unroll
    for (int i = 0; i < 4; ++i) {
      int chb = (i * 4 + w) * 64;
      int ch = chb + l;
      int row = ch >> 3, scc = (ch & 7) ^ (row & 7);
      gload16(xb + (size_t)(m0 + row) * Fn + kt + scc * 8, &As[chb * 8]);
    }
#pragma unroll
    for (int i = 0; i < 4; ++i) {
      int chb = (i * 4 + w) * 64;
      int ch = chb + l;
      int row = ch >> 3, scc = (ch & 7) ^ (row & 7);
      gload16(wp + (size_t)(n0 + row) * Fn + kt + scc * 8, &Bs[chb * 8]);
    }
    __syncthreads();
#pragma unroll
    for (int kk = 0; kk < 2; ++kk) {
      bfrag af[4], bf_[4];
#pragma unroll
      for (int fm = 0; fm < 4; ++fm) {
        int row = wr * 64 + fm * 16 + lr;
        int off = (kk * 4 + lg) ^ (row & 7);
        af[fm] = *(const bfrag*)&As[row * 64 + off * 8];
      }
#pragma unroll
      for (int fn = 0; fn < 4; ++fn) {
        int row = wc * 64 + fn * 16 + lr;
        int off = (kk * 4 + lg) ^ (row & 7);
        bf_[fn] = *(const bfrag*)&Bs[row * 64 + off * 8];
      }
#pragma unroll
      for (int fm = 0; fm < 4; ++fm)
#pragma unroll
        for (int fn = 0; fn < 4; ++fn)
          acc[fm][fn] = mfma16(af[fm], bf_[fn], acc[fm][fn]);
    }
    __syncthreads();
  }

  // epilogue: perm write  (h'=c>>7, c'=(c&127)*8+(j>>7), d=j&127)
#pragma unroll
  for (int fm = 0; fm < 4; ++fm) {
#pragma unroll
    for (int r = 0; r < 4; ++r) {
      int m = m0 + wr * 64 + fm * 16 + lg * 4 + r;
      int b = m >> 10, c = m & 1023;
      int gh = c >> 7;
#pragma unroll
      for (int fn = 0; fn < 4; ++fn) {
        int j = n0 + wc * 64 + fn * 16 + lr;
        float v = (acc[fm][fn][r] + bias[j]) * osc;
        int ii = ((c & 127) << 3) | (j >> 7);
        int d = j & 127;
        size_t idx = (((size_t)(b * 8 + gh) * 1024 + ii) << 7) | d;
        outp[idx] = f2bf(v);
      }
    }
  }
}

// ---------- fused flash attention (32x32 MFMA, in-register P) ----------
// O = softmax(QK^T/sqrt(D))@V - V.  1024 blocks (XCD-swizzled: XCD k owns 16
// whole heads), 4 waves/block, wave owns 32 q-rows (block = 128 q-rows).
// S^T = mfma32(K, Q): lane holds one q-column (q = lane&31), 32/64 kv values
// (partner lane l^32 holds the rest) -> softmax = lane-local tree + 1 shfl.
// P^T rebuilt IN-REGISTER via cvt_pk_bf16 + permlane32_swap (no P LDS trip).
// O^T = mfma32(V^T, P^T): alpha/linv are lane-local scalars.  Epilogue
// transposes O^T through LDS (reusing K/V space) and fuses the -V subtract.
__global__ __launch_bounds__(256, 3)
void attn_kernel(const u16* __restrict__ qp_all, const u16* __restrict__ kp_all,
                 const u16* __restrict__ vp_all, u16* __restrict__ attout) {
  __shared__ u16 smem[64 * 128 + 128 * 64];   // Ks [64kv][128k] | Vt [128d][64kv]
  u16* Ks = smem;
  u16* Vt = smem + 64 * 128;

  // XCD-aware bijective swizzle (1024 % 8 == 0)
  const int bid = blockIdx.x;
  const int wg = (bid & 7) * 128 + (bid >> 3);
  const int bh = wg >> 3;
  const int qt = wg & 7;

  const int tid = threadIdx.x, l = tid & 63, w = tid >> 6;
  const int q31 = l & 31, hi = l >> 5;

  const u16* qp = qp_all + (size_t)bh * (Cn * Dn);
  const u16* kp = kp_all + (size_t)bh * (Cn * Dn);
  const u16* vp = vp_all + (size_t)bh * (Cn * Dn);
  const int qr0 = qt * 128 + w * 32;

  // Q as B-operand frags: lane holds col q=q31, k-slice kk*16 + hi*8 (32 VGPR)
  bfrag aq[8];
#pragma unroll
  for (int kk = 0; kk < 8; ++kk)
    aq[kk] = *(const bfrag*)(qp + (size_t)(qr0 + q31) * Dn + kk * 16 + hi * 8);

  f32x16 ot[4] = {};                 // O^T accumulator: col q=q31, rows d
  float mst = -1e30f, lst = 0.f;     // per-lane (q-row) softmax state

  for (int t = 0; t < 16; ++t) {
    // stage K [64][128]: 1024 chunks of 16B, source pre-swizzled
#pragma unroll
    for (int i = 0; i < 4; ++i) {
      int chb = (i * 4 + w) * 64;
      int ch = chb + l;
      int row = ch >> 4, scc = (ch & 15) ^ (row & 7);
      gload16(kp + (size_t)(t * 64 + row) * Dn + scc * 8, &Ks[chb * 8]);
    }
    // stage V^T via regs (consumed immediately -> no long live range)
    {
      const u16* vr = vp + (size_t)(t * 64 + l) * Dn + w * 32;
#pragma unroll
      for (int i = 0; i < 4; ++i) {
        u16x8 vv = *(const u16x8*)(vr + i * 8);
#pragma unroll
        for (int j2 = 0; j2 < 8; ++j2) {
          int d = w * 32 + i * 8 + j2;
          Vt[d * 64 + (((l >> 3) ^ (d & 7)) << 3) + (l & 7)] = vv[j2];
        }
      }
    }
    __syncthreads();

    // S^T = K Q^T : two 32x32 tiles over kv; lane holds col q=q31,
    // rows kv = tt*32 + (reg&3) + 8*(reg>>2) + 4*hi
    f32x16 st[2] = {};
#pragma unroll
    for (int tt = 0; tt < 2; ++tt) {
#pragma unroll
      for (int kk = 0; kk < 8; ++kk) {
        int row = tt * 32 + q31;                       // kv row (A m-index)
        int off = (2 * kk + hi) ^ (row & 7);
        bfrag kf = *(const bfrag*)&Ks[row * 128 + off * 8];
        st[tt] = mfma32(kf, aq[kk], st[tt]);
      }
    }

    // lane-local online softmax (scores already in exp2 domain via Q scale)
    float mx = st[0][0];
#pragma unroll
    for (int r = 1; r < 16; ++r) mx = fmaxf(mx, st[0][r]);
#pragma unroll
    for (int r = 0; r < 16; ++r) mx = fmaxf(mx, st[1][r]);
    mx = fmaxf(mx, __shfl_xor(mx, 32, 64));
    // T13 defer-max: skip rescale while max growth <= 8 (P bounded by 2^8)
    if (!__all(mx <= mst + 8.f)) {
      float mnew = fmaxf(mst, mx);
      float alpha = exp2f(mst - mnew);
      lst *= alpha;
#pragma unroll
      for (int dt = 0; dt < 4; ++dt)
#pragma unroll
        for (int r = 0; r < 16; ++r) ot[dt][r] *= alpha;
      mst = mnew;
    }
    float rs = 0.f;
#pragma unroll
    for (int tt = 0; tt < 2; ++tt)
#pragma unroll
      for (int r = 0; r < 16; ++r) {
        float pv = exp2f(st[tt][r] - mst);
        st[tt][r] = pv;
        rs += pv;
      }
    rs += __shfl_xor(rs, 32, 64);
    lst += rs;

    // P^T B-operand frags, fully in-register: pack bf16 pairs, swap halves.
    // dest lane(hi) kkt-frag needs kv = tt*32 + 16*kkt + 8*hi + 0..7 :
    //   words {0,1} from hi'=0 lane's c[4kkt+2hi..], words {2,3} from hi'=1;
    //   permlane32_swap(c[4kkt+i], c[4kkt+2+i]) yields both needed words.
    bfrag pb[4];
#pragma unroll
    for (int tt = 0; tt < 2; ++tt) {
      unsigned c[8];
#pragma unroll
      for (int m = 0; m < 8; ++m)
        c[m] = cvtpk(st[tt][2 * m], st[tt][2 * m + 1]);
#pragma unroll
      for (int kkt = 0; kkt < 2; ++kkt) {
        unsigned a0 = c[4 * kkt + 0], b0 = c[4 * kkt + 2];
        unsigned a1 = c[4 * kkt + 1], b1 = c[4 * kkt + 3];
        asm("v_permlane32_swap_b32 %0, %1" : "+v"(a0), "+v"(b0));
        asm("v_permlane32_swap_b32 %0, %1" : "+v"(a1), "+v"(b1));
        u32x4 bw; bw.x = a0; bw.y = a1; bw.z = b0; bw.w = b1;
        pb[tt * 2 + kkt] = __builtin_bit_cast(bfrag, bw);
      }
    }

    // O^T += V^T P^T : 4 d-tiles x 4 k-slices of kv
#pragma unroll
    for (int kk = 0; kk < 4; ++kk) {
#pragma unroll
      for (int dt = 0; dt < 4; ++dt) {
        int d = dt * 32 + q31;                         // d row (A m-index)
        int off = (2 * kk + hi) ^ (d & 7);
        bfrag vf = *(const bfrag*)&Vt[d * 64 + off * 8];
        ot[dt] = mfma32(vf, pb[kk], ot[dt]);
      }
    }
    __syncthreads();  // protect Ks/Vt before next staging (and epilogue reuse)
  }

  // ---- epilogue: O^T/lst -> LDS transpose -> coalesced (O - V) write ----
  float linv = 1.f / lst;
  u16* my = smem + w * (32 * 128);   // per-wave scratch [32 q][128 d], swizzled
#pragma unroll
  for (int dt = 0; dt < 4; ++dt)
#pragma unroll
    for (int rp = 0; rp < 8; ++rp) {
      int reg = 2 * rp;
      int d = dt * 32 + (reg & 3) + 8 * (reg >> 2) + 4 * hi;   // even; d+1 next reg
      unsigned pk = cvtpk(ot[dt][reg] * linv, ot[dt][reg + 1] * linv);
      *(unsigned*)&my[q31 * 128 + (((d >> 3) ^ (q31 & 7)) << 3) + (d & 7)] = pk;
    }
  // same-wave RAW through LDS (lgkmcnt ordered by compiler)
  const int b = bh >> 3, h = bh & 7;
#pragma unroll
  for (int it = 0; it < 8; ++it) {
    int rowq = it * 4 + (l >> 4);
    int ch = l & 15;
    u16x8 rd = *(const u16x8*)&my[rowq * 128 + ((ch ^ (rowq & 7))) * 8];
    int c1 = qr0 + rowq;
    u16x8 vv = *(const u16x8*)&vp[(size_t)c1 * Dn + ch * 8];
    u16x8 ov;
#pragma unroll
    for (int e = 0; e < 8; ++e) ov[e] = f2bf(bf2f(rd[e]) - bf2f(vv[e]));
    *(u16x8*)&attout[(((size_t)(b * 1024 + c1)) * 8 + h) * 128 + ch * 8] = ov;
  }
}

// ---------- output GEMM: [16384][1024] @ [1024][128] + bias -> f32 ----------
__global__ void out_gemm(const u16* __restrict__ A, const u16* __restrict__ Bt,
                         const float* __restrict__ bias, float* __restrict__ out) {
  __shared__ u16 As[64 * 64];
  __shared__ u16 Bs[128 * 64];
  const int m0 = blockIdx.x * 64;
  const int tid = threadIdx.x, l = tid & 63, w = tid >> 6;
  const int lr = l & 15, lg = l >> 4;
  const int wr = w >> 1, wc = w & 1;
  f32x4 acc[2][4] = {};

  for (int kt = 0; kt < 1024; kt += 64) {
#pragma unroll
    for (int i = 0; i < 2; ++i) {
      int chb = (i * 4 + w) * 64;
      int ch = chb + l;
      int row = ch >> 3, scc = (ch & 7) ^ (row & 7);
      gload16(A + (size_t)(m0 + row) * 1024 + kt + scc * 8, &As[chb * 8]);
    }
#pragma unroll
    for (int i = 0; i < 4; ++i) {
      int chb = (i * 4 + w) * 64;
      int ch = chb + l;
      int row = ch >> 3, scc = (ch & 7) ^ (row & 7);
      gload16(Bt + (size_t)row * 1024 + kt + scc * 8, &Bs[chb * 8]);
    }
    __syncthreads();
#pragma unroll
    for (int kk = 0; kk < 2; ++kk) {
      bfrag af[2], bf_[4];
#pragma unroll
      for (int fm = 0; fm < 2; ++fm) {
        int row = wr * 32 + fm * 16 + lr;
        int off = (kk * 4 + lg) ^ (row & 7);
        af[fm] = *(const bfrag*)&As[row * 64 + off * 8];
      }
#pragma unroll
      for (int fn = 0; fn < 4; ++fn) {
        int row = wc * 64 + fn * 16 + lr;
        int off = (kk * 4 + lg) ^ (row & 7);
        bf_[fn] = *(const bfrag*)&Bs[row * 64 + off * 8];
      }
#pragma unroll
      for (int fm = 0; fm < 2; ++fm)
#pragma unroll
        for (int fn = 0; fn < 4; ++fn)
          acc[fm][fn] = mfma16(af[fm], bf_[fn], acc[fm][fn]);
    }
    __syncthreads();
  }
#pragma unroll
  for (int fm = 0; fm < 2; ++fm)
#pragma unroll
    for (int r = 0; r < 4; ++r) {
      int m = m0 + wr * 32 + fm * 16 + lg * 4 + r;
#pragma unroll
      for (int fn = 0; fn < 4; ++fn) {
        int j = wc * 64 + fn * 16 + lr;
        out[(size_t)m * 128 + j] = acc[fm][fn][r] + bias[j];
      }
    }
}

// ---------- launch ----------
extern "C" void kernel_launch(void* const* d_in, const int* in_sizes, int n_in,
                              void* d_out, int out_size, void* d_ws, size_t ws_size,
                              hipStream_t stream) {
  const float* x   = (const float*)d_in[0];
  const float* Wk  = (const float*)d_in[1];
  const float* bk_ = (const float*)d_in[2];
  const float* Wq  = (const float*)d_in[3];
  const float* bq_ = (const float*)d_in[4];
  const float* Wv  = (const float*)d_in[5];
  const float* bv_ = (const float*)d_in[6];
  const float* Ww0 = (const float*)d_in[7];
  const float* bw0 = (const float*)d_in[8];
  float* out = (float*)d_out;

  char* ws = (char*)d_ws;
  u16* xb   = (u16*)(ws + OFF_XB);
  u16* wt   = (u16*)(ws + OFF_WT);
  u16* w0t  = (u16*)(ws + OFF_W0T);
  u16* qpm  = (u16*)(ws + OFF_Q);
  u16* kpm  = (u16*)(ws + OFF_K);
  u16* vpm  = (u16*)(ws + OFF_V);
  u16* attb = (u16*)(ws + OFF_ATT);

  // prep: cast x, transpose+cast weights
  cvt_bf16<<<(M1 * Fn / 4 + 255) / 256, 256, 0, stream>>>(x, xb, M1 * Fn);
  dim3 tb(32, 8);
  transpose_cvt<<<dim3(32, 16), tb, 0, stream>>>(Wq, wt + 0 * 1024 * 512, 512, 1024);
  transpose_cvt<<<dim3(32, 16), tb, 0, stream>>>(Wk, wt + 1 * 1024 * 512, 512, 1024);
  transpose_cvt<<<dim3(32, 16), tb, 0, stream>>>(Wv, wt + 2 * 1024 * 512, 512, 1024);
  transpose_cvt<<<dim3(4, 32),  tb, 0, stream>>>(Ww0, w0t, 1024, 128);

  // projections -> permuted q/k/v (bf16); Q pre-scaled by log2e/sqrt(D)
  qkv_gemm<<<dim3(128, 8, 3), 256, 0, stream>>>(xb, wt, bq_, bk_, bv_, qpm, kpm, vpm);

  // fused attention (softmax - I folded as O = P@V - V), XCD-swizzled grid
  attn_kernel<<<dim3(1024), 256, 0, stream>>>(qpm, kpm, vpm, attb);

  // output projection (f32 out + bias)
  out_gemm<<<256, 256, 0, stream>>>(attb, w0t, bw0, out);
}